// Round 1
// baseline (3879.228 us; speedup 1.0000x reference)
//
#include <hip/hip_runtime.h>
#include <cstddef>

#define B_SZ 8
#define T_SEQ 1024
#define D_MODEL 1024
#define NH 16
#define HD 64
#define TE_DIM 2048
#define BT_ROWS 8192

// ---------------- LayerNorm of x -> xn ----------------
__global__ __launch_bounds__(256) void ln_kernel(
    const float* __restrict__ x, const float* __restrict__ w,
    const float* __restrict__ b, float* __restrict__ out)
{
  __shared__ float red[8];
  int row = blockIdx.x;
  int tid = threadIdx.x;
  const float* xr = x + (size_t)row * D_MODEL;
  float4 xv = *(const float4*)&xr[tid * 4];
  float s  = xv.x + xv.y + xv.z + xv.w;
  float ss = xv.x*xv.x + xv.y*xv.y + xv.z*xv.z + xv.w*xv.w;
  #pragma unroll
  for (int off = 32; off; off >>= 1) {
    s  += __shfl_xor(s, off);
    ss += __shfl_xor(ss, off);
  }
  int wv = tid >> 6;
  if ((tid & 63) == 0) { red[wv] = s; red[4 + wv] = ss; }
  __syncthreads();
  s  = red[0] + red[1] + red[2] + red[3];
  ss = red[4] + red[5] + red[6] + red[7];
  float mean = s * (1.f / D_MODEL);
  float var  = ss * (1.f / D_MODEL) - mean * mean;
  float inv  = rsqrtf(var + 1e-5f);
  float4 w4 = *(const float4*)&w[tid * 4];
  float4 b4 = *(const float4*)&b[tid * 4];
  float4 o;
  o.x = (xv.x - mean) * inv * w4.x + b4.x;
  o.y = (xv.y - mean) * inv * w4.y + b4.y;
  o.z = (xv.z - mean) * inv * w4.z + b4.z;
  o.w = (xv.w - mean) * inv * w4.w + b4.w;
  *(float4*)&out[(size_t)row * D_MODEL + tid * 4] = o;
}

// ---------------- Generic tiled GEMM: C = A@W + bias (+mask)(+residual) ----
// A [M,K], W [K,N] row-major. permute=1: write [B,H,T,64] layout.
__global__ __launch_bounds__(256) void gemm_kernel(
    const float* __restrict__ A, const float* __restrict__ W,
    const float* __restrict__ bias, const float* __restrict__ mask,
    const float* __restrict__ residual, float* __restrict__ C,
    int M, int N, int K, int permute)
{
  __shared__ float As[16][68];
  __shared__ float Bs[16][68];
  int tid = threadIdx.x;
  int tx = tid & 15, ty = tid >> 4;
  int m0 = blockIdx.y * 64, n0 = blockIdx.x * 64;
  int arow = tid >> 2, ak4 = tid & 3;
  int brow = tid >> 4, bc4 = tid & 15;
  const float* Aptr = A + (size_t)(m0 + arow) * K + ak4 * 4;
  const float* Wptr = W + (size_t)brow * N + n0 + bc4 * 4;
  float acc[4][4] = {};
  int nt = K >> 4;
  for (int kt = 0; kt < nt; ++kt) {
    float4 av = *(const float4*)(Aptr + kt * 16);
    float4 bv = *(const float4*)(Wptr + (size_t)kt * 16 * N);
    As[ak4 * 4 + 0][arow] = av.x;
    As[ak4 * 4 + 1][arow] = av.y;
    As[ak4 * 4 + 2][arow] = av.z;
    As[ak4 * 4 + 3][arow] = av.w;
    *(float4*)&Bs[brow][bc4 * 4] = bv;
    __syncthreads();
    #pragma unroll
    for (int kk = 0; kk < 16; ++kk) {
      float4 a4 = *(const float4*)&As[kk][ty * 4];
      float4 b4 = *(const float4*)&Bs[kk][tx * 4];
      float ar[4] = {a4.x, a4.y, a4.z, a4.w};
      float br[4] = {b4.x, b4.y, b4.z, b4.w};
      #pragma unroll
      for (int i = 0; i < 4; i++)
        #pragma unroll
        for (int j = 0; j < 4; j++)
          acc[i][j] = fmaf(ar[i], br[j], acc[i][j]);
    }
    __syncthreads();
  }
  #pragma unroll
  for (int i = 0; i < 4; i++) {
    int gm = m0 + ty * 4 + i;
    float mval = mask ? mask[gm] : 1.f;
    const float* resrow = residual ? residual + (size_t)gm * N : nullptr;
    #pragma unroll
    for (int j = 0; j < 4; j++) {
      int gn = n0 + tx * 4 + j;
      float val = acc[i][j] + bias[gn];
      if (mask) val *= mval;
      if (residual) val += resrow[gn];
      if (permute) {
        int bb = gm >> 10, tt = gm & 1023;
        int hh = gn >> 6, ll = gn & 63;
        C[((size_t)((bb * NH + hh) * T_SEQ + tt)) * HD + ll] = val;
      } else {
        C[(size_t)gm * N + gn] = val;
      }
    }
  }
}

// ---------------- emb: e = silu(emb) @ emb_w + emb_b ----------------
__global__ __launch_bounds__(256) void emb_gemm_kernel(
    const float* __restrict__ emb, const float* __restrict__ emb_w,
    const float* __restrict__ emb_b, float* __restrict__ e)
{
  __shared__ float ses[TE_DIM];
  int bb = blockIdx.y;
  int n = blockIdx.x * 256 + threadIdx.x;
  for (int i = threadIdx.x; i < TE_DIM; i += 256) {
    float v = emb[bb * TE_DIM + i];
    ses[i] = v / (1.f + __expf(-v));
  }
  __syncthreads();
  float acc = emb_b[n];
  #pragma unroll 8
  for (int t = 0; t < TE_DIM; ++t)
    acc = fmaf(ses[t], emb_w[(size_t)t * (2 * D_MODEL) + n], acc);
  e[bb * (2 * D_MODEL) + n] = acc;
}

// ---------------- flash attention: y = softmax(QK^T + maskbias) @ V --------
// q,k,v layout [B,H,T,64]; y written as [B,T,D] (d = h*64+l)
__global__ __launch_bounds__(256) void attn_kernel(
    const float* __restrict__ q, const float* __restrict__ k,
    const float* __restrict__ v, const float* __restrict__ mask,
    float* __restrict__ y)
{
  __shared__ float kst[64][68];  // [dim][key] (transposed)
  __shared__ float vs[64][68];   // [key][dim]
  __shared__ float qs[4][64];
  __shared__ float ps[4][64];
  int bb = blockIdx.z, hh = blockIdx.y;
  int w = threadIdx.x >> 6, lane = threadIdx.x & 63;
  int t = blockIdx.x * 4 + w;
  size_t headbase = (size_t)(bb * NH + hh) * T_SEQ * HD;
  qs[w][lane] = q[headbase + (size_t)t * HD + lane];
  const float* kb = k + headbase;
  const float* vb = v + headbase;
  float m = -1e30f, l = 0.f, yacc = 0.f;
  for (int kt = 0; kt < T_SEQ / 64; ++kt) {
    __syncthreads();
    #pragma unroll
    for (int i = 0; i < 4; ++i) {
      int idx = threadIdx.x + i * 256;   // float4 index 0..1023
      int row = idx >> 4, c4 = idx & 15;
      float4 kv = *(const float4*)&kb[(size_t)(kt * 64 + row) * HD + c4 * 4];
      kst[c4 * 4 + 0][row] = kv.x;
      kst[c4 * 4 + 1][row] = kv.y;
      kst[c4 * 4 + 2][row] = kv.z;
      kst[c4 * 4 + 3][row] = kv.w;
      *(float4*)&vs[row][c4 * 4] =
          *(const float4*)&vb[(size_t)(kt * 64 + row) * HD + c4 * 4];
    }
    __syncthreads();
    float s = 0.f;
    #pragma unroll 16
    for (int i = 0; i < 64; ++i)
      s = fmaf(qs[w][i], kst[i][lane], s);
    float mk = mask[bb * T_SEQ + kt * 64 + lane];
    s += (1.f - mk) * -1000000.0f;
    float tmax = s;
    #pragma unroll
    for (int off = 32; off; off >>= 1) tmax = fmaxf(tmax, __shfl_xor(tmax, off));
    float mnew = fmaxf(m, tmax);
    float corr = __expf(m - mnew);
    float p = __expf(s - mnew);
    float psum = p;
    #pragma unroll
    for (int off = 32; off; off >>= 1) psum += __shfl_xor(psum, off);
    l = l * corr + psum;
    m = mnew;
    ps[w][lane] = p;
    yacc *= corr;
    #pragma unroll 16
    for (int i = 0; i < 64; ++i)
      yacc = fmaf(ps[w][i], vs[i][lane], yacc);
  }
  y[(size_t)(bb * T_SEQ + t) * D_MODEL + hh * HD + lane] = yacc / l;
}

// -------- LN(y)*(1+scale)+shift, then SiLU -> g ----------
__global__ __launch_bounds__(256) void ln2_kernel(
    const float* __restrict__ y, const float* __restrict__ w,
    const float* __restrict__ b, const float* __restrict__ e,
    float* __restrict__ g)
{
  __shared__ float red[8];
  int row = blockIdx.x;
  int tid = threadIdx.x;
  int bb = row >> 10;
  float4 yv = *(const float4*)&y[(size_t)row * D_MODEL + tid * 4];
  float s  = yv.x + yv.y + yv.z + yv.w;
  float ss = yv.x*yv.x + yv.y*yv.y + yv.z*yv.z + yv.w*yv.w;
  #pragma unroll
  for (int off = 32; off; off >>= 1) {
    s  += __shfl_xor(s, off);
    ss += __shfl_xor(ss, off);
  }
  int wv = tid >> 6;
  if ((tid & 63) == 0) { red[wv] = s; red[4 + wv] = ss; }
  __syncthreads();
  s  = red[0] + red[1] + red[2] + red[3];
  ss = red[4] + red[5] + red[6] + red[7];
  float mean = s * (1.f / D_MODEL);
  float var  = ss * (1.f / D_MODEL) - mean * mean;
  float inv  = rsqrtf(var + 1e-5f);
  float vals[4] = {yv.x, yv.y, yv.z, yv.w};
  float4 o;
  float* op = (float*)&o;
  #pragma unroll
  for (int j = 0; j < 4; j++) {
    int c = tid * 4 + j;
    float val = (vals[j] - mean) * inv * w[c] + b[c];
    float sc = e[bb * (2 * D_MODEL) + c];
    float sh = e[bb * (2 * D_MODEL) + D_MODEL + c];
    val = val * (1.f + sc) + sh;
    op[j] = val / (1.f + __expf(-val));
  }
  *(float4*)&g[(size_t)row * D_MODEL + tid * 4] = o;
}

extern "C" void kernel_launch(void* const* d_in, const int* in_sizes, int n_in,
                              void* d_out, int out_size, void* d_ws, size_t ws_size,
                              hipStream_t stream) {
  const float* x      = (const float*)d_in[0];
  const float* emb    = (const float*)d_in[1];
  const float* mask   = (const float*)d_in[2];
  const float* norm_w = (const float*)d_in[3];
  const float* norm_b = (const float*)d_in[4];
  const float* q_w    = (const float*)d_in[5];
  const float* q_b    = (const float*)d_in[6];
  const float* k_w    = (const float*)d_in[7];
  const float* k_b    = (const float*)d_in[8];
  const float* v_w    = (const float*)d_in[9];
  const float* v_b    = (const float*)d_in[10];
  const float* emb_w  = (const float*)d_in[11];
  const float* emb_b  = (const float*)d_in[12];
  const float* sb_w   = (const float*)d_in[13];
  const float* sb_b   = (const float*)d_in[14];
  const float* out_w  = (const float*)d_in[15];
  const float* out_b  = (const float*)d_in[16];
  float* out = (float*)d_out;

  char* ws = (char*)d_ws;
  const size_t MB32 = (size_t)BT_ROWS * D_MODEL * sizeof(float);  // 32 MB
  float* xn = (float*)(ws);              // later reused as y
  float* qb = (float*)(ws + MB32);       // later reused as g
  float* kb = (float*)(ws + 2 * MB32);
  float* vb = (float*)(ws + 3 * MB32);
  float* eb = (float*)(ws + 4 * MB32);   // [B, 2D]

  // 1. xn = LN(x)
  ln_kernel<<<BT_ROWS, 256, 0, stream>>>(x, norm_w, norm_b, xn);

  // 2-4. Q,K,V GEMMs (permuted to [B,H,T,64]; V masked)
  dim3 gg(D_MODEL / 64, BT_ROWS / 64);
  gemm_kernel<<<gg, 256, 0, stream>>>(xn, q_w, q_b, nullptr, nullptr, qb,
                                      BT_ROWS, D_MODEL, D_MODEL, 1);
  gemm_kernel<<<gg, 256, 0, stream>>>(xn, k_w, k_b, nullptr, nullptr, kb,
                                      BT_ROWS, D_MODEL, D_MODEL, 1);
  gemm_kernel<<<gg, 256, 0, stream>>>(xn, v_w, v_b, mask, nullptr, vb,
                                      BT_ROWS, D_MODEL, D_MODEL, 1);

  // 5. e = silu(emb) @ emb_w + emb_b
  emb_gemm_kernel<<<dim3((2 * D_MODEL) / 256, B_SZ), 256, 0, stream>>>(
      emb, emb_w, emb_b, eb);

  // 6. attention -> y (reuse xn buffer)
  attn_kernel<<<dim3(T_SEQ / 4, NH, B_SZ), 256, 0, stream>>>(qb, kb, vb, mask, xn);

  // 7. g = silu(LN(y)*(1+scale)+shift) (reuse q buffer)
  ln2_kernel<<<BT_ROWS, 256, 0, stream>>>(xn, sb_w, sb_b, eb, qb);

  // 8. out = x + g @ out_w + out_b
  gemm_kernel<<<gg, 256, 0, stream>>>(qb, out_w, out_b, nullptr, x, out,
                                      BT_ROWS, D_MODEL, D_MODEL, 0);
}

// Round 2
// 539.743 us; speedup vs baseline: 7.1872x; 7.1872x over previous
//
#include <hip/hip_runtime.h>
#include <cstddef>
#include <cstdint>

#define B_SZ 8
#define T_SEQ 1024
#define D_MODEL 1024
#define NH 16
#define HD 64
#define TE_DIM 2048
#define BT_ROWS 8192

typedef short bf16x8 __attribute__((ext_vector_type(8)));
typedef float f32x4 __attribute__((ext_vector_type(4)));

#define MFMA16(a, b, c) __builtin_amdgcn_mfma_f32_16x16x32_bf16(a, b, c, 0, 0, 0)

__device__ inline unsigned short f2b(float f) {
  union { float f; unsigned u; } v; v.f = f;
  unsigned r = v.u + 0x7FFF + ((v.u >> 16) & 1);
  return (unsigned short)(r >> 16);
}

// ---------------- LayerNorm of x -> xn (bf16) ----------------
__global__ __launch_bounds__(256) void ln_kernel(
    const float* __restrict__ x, const float* __restrict__ w,
    const float* __restrict__ b, unsigned short* __restrict__ out)
{
  __shared__ float red[8];
  int row = blockIdx.x;
  int tid = threadIdx.x;
  const float* xr = x + (size_t)row * D_MODEL;
  float4 xv = *(const float4*)&xr[tid * 4];
  float s  = xv.x + xv.y + xv.z + xv.w;
  float ss = xv.x*xv.x + xv.y*xv.y + xv.z*xv.z + xv.w*xv.w;
  #pragma unroll
  for (int off = 32; off; off >>= 1) {
    s  += __shfl_xor(s, off);
    ss += __shfl_xor(ss, off);
  }
  int wv = tid >> 6;
  if ((tid & 63) == 0) { red[wv] = s; red[4 + wv] = ss; }
  __syncthreads();
  s  = red[0] + red[1] + red[2] + red[3];
  ss = red[4] + red[5] + red[6] + red[7];
  float mean = s * (1.f / D_MODEL);
  float var  = ss * (1.f / D_MODEL) - mean * mean;
  float inv  = rsqrtf(var + 1e-5f);
  float4 w4 = *(const float4*)&w[tid * 4];
  float4 b4 = *(const float4*)&b[tid * 4];
  ushort4 o;
  o.x = f2b((xv.x - mean) * inv * w4.x + b4.x);
  o.y = f2b((xv.y - mean) * inv * w4.y + b4.y);
  o.z = f2b((xv.z - mean) * inv * w4.z + b4.z);
  o.w = f2b((xv.w - mean) * inv * w4.w + b4.w);
  *(ushort4*)&out[(size_t)row * D_MODEL + tid * 4] = o;
}

// ---------------- weight transpose fp32 [K][N] -> bf16 [N][K] ----------------
__global__ __launch_bounds__(256) void transpose_w(
    const float* __restrict__ in, unsigned short* __restrict__ out)
{
  __shared__ float s[32][33];
  int tx = threadIdx.x & 31, ty = threadIdx.x >> 5;  // ty 0..7
  int r0 = blockIdx.y * 32, c0 = blockIdx.x * 32;
  #pragma unroll
  for (int rr = 0; rr < 4; ++rr)
    s[ty + rr * 8][tx] = in[(size_t)(r0 + ty + rr * 8) * D_MODEL + c0 + tx];
  __syncthreads();
  #pragma unroll
  for (int rr = 0; rr < 4; ++rr)
    out[(size_t)(c0 + ty + rr * 8) * D_MODEL + r0 + tx] = f2b(s[tx][ty + rr * 8]);
}

// ---------------- bf16 MFMA GEMM: C = A @ Bt^T + bias ----------------
// A [M][1024] bf16, Bt [N][1024] bf16 (pre-transposed weight)
// mode 0: fp32 [M][N], += resid     mode 1: bf16 [B,H,T,64]
// mode 2: bf16 [B,H,64,T], *= mask[m]
__global__ __launch_bounds__(256) void gemm_bf16(
    const unsigned short* __restrict__ A, const unsigned short* __restrict__ Bt,
    const float* __restrict__ bias, const float* __restrict__ mask,
    const float* __restrict__ resid, void* __restrict__ C, int mode)
{
  const int K = 1024;
  __shared__ unsigned short As[128 * 64];
  __shared__ unsigned short Bs[128 * 64];
  int tid = threadIdx.x;
  int lane = tid & 63, w = tid >> 6;
  int g = lane >> 4, lq = lane & 15;
  int wr = w >> 1, wc = w & 1;
  int m0 = blockIdx.y * 128, n0 = blockIdx.x * 128;
  f32x4 acc[4][4];
  #pragma unroll
  for (int i = 0; i < 4; ++i)
    #pragma unroll
    for (int j = 0; j < 4; ++j)
      acc[i][j] = (f32x4){0.f, 0.f, 0.f, 0.f};

  for (int k0 = 0; k0 < K; k0 += 64) {
    #pragma unroll
    for (int it = 0; it < 4; ++it) {
      int chunk = it * 256 + tid;
      int r = chunk >> 3, cb = chunk & 7;
      int lo = r * 128 + ((cb ^ (r & 7)) * 16);
      *(uint4*)((char*)As + lo) = *(const uint4*)(A + (size_t)(m0 + r) * K + k0 + cb * 8);
      *(uint4*)((char*)Bs + lo) = *(const uint4*)(Bt + (size_t)(n0 + r) * K + k0 + cb * 8);
    }
    __syncthreads();
    #pragma unroll
    for (int kh = 0; kh < 2; ++kh) {
      bf16x8 af[4], bfr[4];
      #pragma unroll
      for (int i = 0; i < 4; ++i) {
        int ra = wr * 64 + i * 16 + lq;
        af[i] = *(const bf16x8*)((const char*)As + ra * 128 + (((kh * 4 + g) ^ (ra & 7)) * 16));
        int rb = wc * 64 + i * 16 + lq;
        bfr[i] = *(const bf16x8*)((const char*)Bs + rb * 128 + (((kh * 4 + g) ^ (rb & 7)) * 16));
      }
      #pragma unroll
      for (int i = 0; i < 4; ++i)
        #pragma unroll
        for (int j = 0; j < 4; ++j)
          acc[i][j] = MFMA16(af[i], bfr[j], acc[i][j]);
    }
    __syncthreads();
  }

  int colbase = n0 + wc * 64;
  #pragma unroll
  for (int i = 0; i < 4; ++i) {
    int mrow0 = m0 + wr * 64 + i * 16 + g * 4;
    #pragma unroll
    for (int j = 0; j < 4; ++j) {
      int n = colbase + j * 16 + lq;
      float bv = bias[n];
      if (mode == 0) {
        float* Cf = (float*)C;
        #pragma unroll
        for (int rr = 0; rr < 4; ++rr) {
          int m = mrow0 + rr;
          Cf[(size_t)m * D_MODEL + n] = acc[i][j][rr] + bv + resid[(size_t)m * D_MODEL + n];
        }
      } else if (mode == 1) {
        unsigned short* Cb = (unsigned short*)C;
        int h = n >> 6, dd = n & 63;
        #pragma unroll
        for (int rr = 0; rr < 4; ++rr) {
          int m = mrow0 + rr;
          int b = m >> 10, t = m & 1023;
          Cb[((size_t)((b * NH + h) * T_SEQ + t)) * HD + dd] = f2b(acc[i][j][rr] + bv);
        }
      } else {
        unsigned short* Cb = (unsigned short*)C;
        int h = n >> 6, dd = n & 63;
        int b = mrow0 >> 10, t = mrow0 & 1023;
        ushort4 pk;
        unsigned short* pp = (unsigned short*)&pk;
        #pragma unroll
        for (int rr = 0; rr < 4; ++rr)
          pp[rr] = f2b((acc[i][j][rr] + bv) * mask[mrow0 + rr]);
        *(ushort4*)&Cb[((size_t)((b * NH + h) * HD + dd)) * T_SEQ + t] = pk;
      }
    }
  }
}

// ---------------- emb: e = silu(emb) @ emb_w + emb_b ----------------
__global__ __launch_bounds__(256) void emb_gemm2(
    const float* __restrict__ emb, const float* __restrict__ emb_w,
    const float* __restrict__ emb_b, float* __restrict__ e)
{
  __shared__ float ses[B_SZ][TE_DIM];
  int n = blockIdx.x * 256 + threadIdx.x;
  for (int i = threadIdx.x; i < B_SZ * TE_DIM; i += 256) {
    int bb = i >> 11, t = i & (TE_DIM - 1);
    float v = emb[bb * TE_DIM + t];
    ses[bb][t] = v / (1.f + __expf(-v));
  }
  __syncthreads();
  float acc[B_SZ];
  #pragma unroll
  for (int bb = 0; bb < B_SZ; ++bb) acc[bb] = 0.f;
  for (int t = 0; t < TE_DIM; ++t) {
    float wv = emb_w[(size_t)t * (2 * D_MODEL) + n];
    #pragma unroll
    for (int bb = 0; bb < B_SZ; ++bb)
      acc[bb] = fmaf(ses[bb][t], wv, acc[bb]);
  }
  float bv = emb_b[n];
  #pragma unroll
  for (int bb = 0; bb < B_SZ; ++bb)
    e[bb * (2 * D_MODEL) + n] = acc[bb] + bv;
}

// ---------------- MFMA flash attention ----------------
// Q,K bf16 [B,H,T,64]; Vt bf16 [B,H,64,T]; y fp32 [B,T,D]
// Swapped operands: S^T = K.Q^T so key-reduction is lane-local-ish.
__global__ __launch_bounds__(256) void attn_mfma(
    const unsigned short* __restrict__ Q, const unsigned short* __restrict__ K,
    const unsigned short* __restrict__ Vt, const float* __restrict__ mask,
    float* __restrict__ y)
{
  __shared__ unsigned short P[4][16][72];   // per-wave P^T buffer, padded
  int tid = threadIdx.x;
  int w = tid >> 6, lane = tid & 63;
  int g = lane >> 4, lq = lane & 15;
  int b = blockIdx.z, h = blockIdx.y;
  int q0 = blockIdx.x * 64 + w * 16;
  size_t hb = ((size_t)(b * NH + h)) * T_SEQ * HD;  // elem base (same for Vt)
  const unsigned short* qrow = Q + hb + (size_t)(q0 + lq) * HD;
  bf16x8 bq0 = *(const bf16x8*)(qrow + g * 8);
  bf16x8 bq1 = *(const bf16x8*)(qrow + 32 + g * 8);
  f32x4 o[4];
  #pragma unroll
  for (int dt = 0; dt < 4; ++dt) o[dt] = (f32x4){0.f, 0.f, 0.f, 0.f};
  float mrun = -3.0e38f, lrun = 0.f;
  unsigned short* Pw = &P[w][0][0];
  const float* maskb = mask + b * T_SEQ;

  for (int kv0 = 0; kv0 < T_SEQ; kv0 += 64) {
    // S^T tiles: st[kt] holds S^T[kv0+kt*16+g*4+r][q0+lq]
    f32x4 st[4];
    #pragma unroll
    for (int kt = 0; kt < 4; ++kt) {
      st[kt] = (f32x4){0.f, 0.f, 0.f, 0.f};
      const unsigned short* krow = K + hb + (size_t)(kv0 + kt * 16 + lq) * HD;
      st[kt] = MFMA16(*(const bf16x8*)(krow + g * 8), bq0, st[kt]);
      st[kt] = MFMA16(*(const bf16x8*)(krow + 32 + g * 8), bq1, st[kt]);
      float4 mk = *(const float4*)&maskb[kv0 + kt * 16 + g * 4];
      st[kt][0] += (1.f - mk.x) * -1000000.f;
      st[kt][1] += (1.f - mk.y) * -1000000.f;
      st[kt][2] += (1.f - mk.z) * -1000000.f;
      st[kt][3] += (1.f - mk.w) * -1000000.f;
    }
    // online softmax over kv (per column q = lane&15; 4 lanes share q)
    float tmax = -3.0e38f;
    #pragma unroll
    for (int kt = 0; kt < 4; ++kt)
      #pragma unroll
      for (int r = 0; r < 4; ++r) tmax = fmaxf(tmax, st[kt][r]);
    tmax = fmaxf(tmax, __shfl_xor(tmax, 16));
    tmax = fmaxf(tmax, __shfl_xor(tmax, 32));
    float mnew = fmaxf(mrun, tmax);
    float corr = __expf(mrun - mnew);
    float psum = 0.f;
    #pragma unroll
    for (int kt = 0; kt < 4; ++kt)
      #pragma unroll
      for (int r = 0; r < 4; ++r) {
        float p = __expf(st[kt][r] - mnew);
        st[kt][r] = p;
        psum += p;
      }
    psum += __shfl_xor(psum, 16);
    psum += __shfl_xor(psum, 32);
    lrun = lrun * corr + psum;
    mrun = mnew;
    #pragma unroll
    for (int dt = 0; dt < 4; ++dt) {
      o[dt][0] *= corr; o[dt][1] *= corr; o[dt][2] *= corr; o[dt][3] *= corr;
    }
    // P^T -> LDS (bf16), per-wave private, padded stride 72
    #pragma unroll
    for (int kt = 0; kt < 4; ++kt) {
      ushort4 pk;
      pk.x = f2b(st[kt][0]); pk.y = f2b(st[kt][1]);
      pk.z = f2b(st[kt][2]); pk.w = f2b(st[kt][3]);
      *(ushort4*)(Pw + lq * 72 + kt * 16 + g * 4) = pk;
    }
    // O^T += V^T . P^T
    #pragma unroll
    for (int kh = 0; kh < 2; ++kh) {
      bf16x8 pb = *(const bf16x8*)(Pw + lq * 72 + kh * 32 + g * 8);
      #pragma unroll
      for (int dt = 0; dt < 4; ++dt) {
        const unsigned short* vrow =
            Vt + hb + (size_t)(dt * 16 + lq) * T_SEQ + kv0 + kh * 32 + g * 8;
        o[dt] = MFMA16(*(const bf16x8*)vrow, pb, o[dt]);
      }
    }
  }
  float inv = 1.f / lrun;
  #pragma unroll
  for (int dt = 0; dt < 4; ++dt) {
    float4 ov;
    ov.x = o[dt][0] * inv; ov.y = o[dt][1] * inv;
    ov.z = o[dt][2] * inv; ov.w = o[dt][3] * inv;
    *(float4*)&y[(size_t)(b * T_SEQ + q0 + lq) * D_MODEL + h * HD + dt * 16 + g * 4] = ov;
  }
}

// -------- g = silu(LN(y)*(1+scale)+shift)  (bf16 out) ----------
__global__ __launch_bounds__(256) void ln2_kernel(
    const float* __restrict__ y, const float* __restrict__ w,
    const float* __restrict__ b, const float* __restrict__ e,
    unsigned short* __restrict__ gout)
{
  __shared__ float red[8];
  int row = blockIdx.x;
  int tid = threadIdx.x;
  int bb = row >> 10;
  float4 yv = *(const float4*)&y[(size_t)row * D_MODEL + tid * 4];
  float s  = yv.x + yv.y + yv.z + yv.w;
  float ss = yv.x*yv.x + yv.y*yv.y + yv.z*yv.z + yv.w*yv.w;
  #pragma unroll
  for (int off = 32; off; off >>= 1) {
    s  += __shfl_xor(s, off);
    ss += __shfl_xor(ss, off);
  }
  int wv = tid >> 6;
  if ((tid & 63) == 0) { red[wv] = s; red[4 + wv] = ss; }
  __syncthreads();
  s  = red[0] + red[1] + red[2] + red[3];
  ss = red[4] + red[5] + red[6] + red[7];
  float mean = s * (1.f / D_MODEL);
  float var  = ss * (1.f / D_MODEL) - mean * mean;
  float inv  = rsqrtf(var + 1e-5f);
  float vals[4] = {yv.x, yv.y, yv.z, yv.w};
  ushort4 o;
  unsigned short* op = (unsigned short*)&o;
  #pragma unroll
  for (int j = 0; j < 4; j++) {
    int c = tid * 4 + j;
    float val = (vals[j] - mean) * inv * w[c] + b[c];
    float sc = e[bb * (2 * D_MODEL) + c];
    float sh = e[bb * (2 * D_MODEL) + D_MODEL + c];
    val = val * (1.f + sc) + sh;
    op[j] = f2b(val / (1.f + __expf(-val)));
  }
  *(ushort4*)&gout[(size_t)row * D_MODEL + tid * 4] = o;
}

extern "C" void kernel_launch(void* const* d_in, const int* in_sizes, int n_in,
                              void* d_out, int out_size, void* d_ws, size_t ws_size,
                              hipStream_t stream) {
  const float* x      = (const float*)d_in[0];
  const float* emb    = (const float*)d_in[1];
  const float* mask   = (const float*)d_in[2];
  const float* norm_w = (const float*)d_in[3];
  const float* norm_b = (const float*)d_in[4];
  const float* q_w    = (const float*)d_in[5];
  const float* q_b    = (const float*)d_in[6];
  const float* k_w    = (const float*)d_in[7];
  const float* k_b    = (const float*)d_in[8];
  const float* v_w    = (const float*)d_in[9];
  const float* v_b    = (const float*)d_in[10];
  const float* emb_w  = (const float*)d_in[11];
  const float* emb_b  = (const float*)d_in[12];
  const float* sb_w   = (const float*)d_in[13];
  const float* sb_b   = (const float*)d_in[14];
  const float* out_w  = (const float*)d_in[15];
  const float* out_b  = (const float*)d_in[16];
  float* out = (float*)d_out;

  char* ws = (char*)d_ws;
  const size_t MB = 1u << 20;
  unsigned short* xn  = (unsigned short*)(ws);             // 16 MB bf16 [8192][1024]
  unsigned short* qb  = (unsigned short*)(ws + 16 * MB);   // 16 MB [B,H,T,64]
  unsigned short* kb  = (unsigned short*)(ws + 32 * MB);   // 16 MB [B,H,T,64]
  unsigned short* vt  = (unsigned short*)(ws + 48 * MB);   // 16 MB [B,H,64,T]
  float*          yb  = (float*)(ws + 64 * MB);            // 32 MB fp32 [B,T,D]
  unsigned short* gb  = (unsigned short*)(ws + 96 * MB);   // 16 MB bf16
  unsigned short* qwt = (unsigned short*)(ws + 112 * MB);  // 2 MB each
  unsigned short* kwt = (unsigned short*)(ws + 114 * MB);
  unsigned short* vwt = (unsigned short*)(ws + 116 * MB);
  unsigned short* owt = (unsigned short*)(ws + 118 * MB);
  float*          eb  = (float*)(ws + 120 * MB);           // 64 KB [B][2D]

  dim3 tg(32, 32);
  transpose_w<<<tg, 256, 0, stream>>>(q_w, qwt);
  transpose_w<<<tg, 256, 0, stream>>>(k_w, kwt);
  transpose_w<<<tg, 256, 0, stream>>>(v_w, vwt);
  transpose_w<<<tg, 256, 0, stream>>>(out_w, owt);

  ln_kernel<<<BT_ROWS, 256, 0, stream>>>(x, norm_w, norm_b, xn);

  dim3 gg(D_MODEL / 128, BT_ROWS / 128);
  gemm_bf16<<<gg, 256, 0, stream>>>(xn, qwt, q_b, nullptr, nullptr, qb, 1);
  gemm_bf16<<<gg, 256, 0, stream>>>(xn, kwt, k_b, nullptr, nullptr, kb, 1);
  gemm_bf16<<<gg, 256, 0, stream>>>(xn, vwt, v_b, mask, nullptr, vt, 2);

  emb_gemm2<<<(2 * D_MODEL) / 256, 256, 0, stream>>>(emb, emb_w, emb_b, eb);

  attn_mfma<<<dim3(T_SEQ / 64, NH, B_SZ), 256, 0, stream>>>(qb, kb, vt, mask, yb);

  ln2_kernel<<<BT_ROWS, 256, 0, stream>>>(yb, sb_w, sb_b, eb, gb);

  gemm_bf16<<<gg, 256, 0, stream>>>(gb, owt, out_b, nullptr, x, out, 0);
}

// Round 3
// 376.252 us; speedup vs baseline: 10.3102x; 1.4345x over previous
//
#include <hip/hip_runtime.h>
#include <cstddef>
#include <cstdint>

#define B_SZ 8
#define T_SEQ 1024
#define D_MODEL 1024
#define NH 16
#define HD 64
#define TE_DIM 2048
#define BT_ROWS 8192

typedef short bf16x8 __attribute__((ext_vector_type(8)));
typedef float f32x4 __attribute__((ext_vector_type(4)));

#define MFMA16(a, b, c) __builtin_amdgcn_mfma_f32_16x16x32_bf16(a, b, c, 0, 0, 0)

__device__ inline unsigned short f2b(float f) {
  union { float f; unsigned u; } v; v.f = f;
  unsigned r = v.u + 0x7FFF + ((v.u >> 16) & 1);
  return (unsigned short)(r >> 16);
}

__device__ inline void gll16(const void* g, void* l) {
  __builtin_amdgcn_global_load_lds(
      (const __attribute__((address_space(1))) unsigned int*)g,
      (__attribute__((address_space(3))) unsigned int*)l, 16, 0, 0);
}

// ---------------- LayerNorm of x -> xn (bf16) ----------------
__global__ __launch_bounds__(256) void ln_kernel(
    const float* __restrict__ x, const float* __restrict__ w,
    const float* __restrict__ b, unsigned short* __restrict__ out)
{
  __shared__ float red[8];
  int row = blockIdx.x;
  int tid = threadIdx.x;
  const float* xr = x + (size_t)row * D_MODEL;
  float4 xv = *(const float4*)&xr[tid * 4];
  float s  = xv.x + xv.y + xv.z + xv.w;
  float ss = xv.x*xv.x + xv.y*xv.y + xv.z*xv.z + xv.w*xv.w;
  #pragma unroll
  for (int off = 32; off; off >>= 1) {
    s  += __shfl_xor(s, off);
    ss += __shfl_xor(ss, off);
  }
  int wv = tid >> 6;
  if ((tid & 63) == 0) { red[wv] = s; red[4 + wv] = ss; }
  __syncthreads();
  s  = red[0] + red[1] + red[2] + red[3];
  ss = red[4] + red[5] + red[6] + red[7];
  float mean = s * (1.f / D_MODEL);
  float var  = ss * (1.f / D_MODEL) - mean * mean;
  float inv  = rsqrtf(var + 1e-5f);
  float4 w4 = *(const float4*)&w[tid * 4];
  float4 b4 = *(const float4*)&b[tid * 4];
  ushort4 o;
  o.x = f2b((xv.x - mean) * inv * w4.x + b4.x);
  o.y = f2b((xv.y - mean) * inv * w4.y + b4.y);
  o.z = f2b((xv.z - mean) * inv * w4.z + b4.z);
  o.w = f2b((xv.w - mean) * inv * w4.w + b4.w);
  *(ushort4*)&out[(size_t)row * D_MODEL + tid * 4] = o;
}

// ---------------- weight transpose fp32 [K][N] -> bf16 [N][K] ----------------
__global__ __launch_bounds__(256) void transpose_w(
    const float* __restrict__ in, unsigned short* __restrict__ out)
{
  __shared__ float s[32][33];
  int tx = threadIdx.x & 31, ty = threadIdx.x >> 5;  // ty 0..7
  int r0 = blockIdx.y * 32, c0 = blockIdx.x * 32;
  #pragma unroll
  for (int rr = 0; rr < 4; ++rr)
    s[ty + rr * 8][tx] = in[(size_t)(r0 + ty + rr * 8) * D_MODEL + c0 + tx];
  __syncthreads();
  #pragma unroll
  for (int rr = 0; rr < 4; ++rr)
    out[(size_t)(c0 + ty + rr * 8) * D_MODEL + r0 + tx] = f2b(s[tx][ty + rr * 8]);
}

// ---------------- bf16 MFMA GEMM: C = A @ Bt^T + bias ----------------
// A [M][1024] bf16, Bt [N][1024] bf16 (pre-transposed weight)
// mode 0: fp32 [M][N], += resid     mode 1: bf16 [B,H,T,64]
// mode 2: bf16 [B,H,64,T], *= mask[m]
__global__ __launch_bounds__(256) void gemm_bf16(
    const unsigned short* __restrict__ A, const unsigned short* __restrict__ Bt,
    const float* __restrict__ bias, const float* __restrict__ mask,
    const float* __restrict__ resid, void* __restrict__ C, int mode)
{
  const int K = 1024;
  __shared__ unsigned short As[128 * 64];
  __shared__ unsigned short Bs[128 * 64];
  int tid = threadIdx.x;
  int lane = tid & 63, w = tid >> 6;
  int g = lane >> 4, lq = lane & 15;
  int wr = w >> 1, wc = w & 1;
  int m0 = blockIdx.y * 128, n0 = blockIdx.x * 128;
  f32x4 acc[4][4];
  #pragma unroll
  for (int i = 0; i < 4; ++i)
    #pragma unroll
    for (int j = 0; j < 4; ++j)
      acc[i][j] = (f32x4){0.f, 0.f, 0.f, 0.f};

  for (int k0 = 0; k0 < K; k0 += 64) {
    #pragma unroll
    for (int it = 0; it < 4; ++it) {
      int chunk = it * 256 + tid;
      int r = chunk >> 3, cb = chunk & 7;
      int lo = r * 128 + ((cb ^ (r & 7)) * 16);
      *(uint4*)((char*)As + lo) = *(const uint4*)(A + (size_t)(m0 + r) * K + k0 + cb * 8);
      *(uint4*)((char*)Bs + lo) = *(const uint4*)(Bt + (size_t)(n0 + r) * K + k0 + cb * 8);
    }
    __syncthreads();
    #pragma unroll
    for (int kh = 0; kh < 2; ++kh) {
      bf16x8 af[4], bfr[4];
      #pragma unroll
      for (int i = 0; i < 4; ++i) {
        int ra = wr * 64 + i * 16 + lq;
        af[i] = *(const bf16x8*)((const char*)As + ra * 128 + (((kh * 4 + g) ^ (ra & 7)) * 16));
        int rb = wc * 64 + i * 16 + lq;
        bfr[i] = *(const bf16x8*)((const char*)Bs + rb * 128 + (((kh * 4 + g) ^ (rb & 7)) * 16));
      }
      #pragma unroll
      for (int i = 0; i < 4; ++i)
        #pragma unroll
        for (int j = 0; j < 4; ++j)
          acc[i][j] = MFMA16(af[i], bfr[j], acc[i][j]);
    }
    __syncthreads();
  }

  int colbase = n0 + wc * 64;
  #pragma unroll
  for (int i = 0; i < 4; ++i) {
    int mrow0 = m0 + wr * 64 + i * 16 + g * 4;
    #pragma unroll
    for (int j = 0; j < 4; ++j) {
      int n = colbase + j * 16 + lq;
      float bv = bias[n];
      if (mode == 0) {
        float* Cf = (float*)C;
        #pragma unroll
        for (int rr = 0; rr < 4; ++rr) {
          int m = mrow0 + rr;
          Cf[(size_t)m * D_MODEL + n] = acc[i][j][rr] + bv + resid[(size_t)m * D_MODEL + n];
        }
      } else if (mode == 1) {
        unsigned short* Cb = (unsigned short*)C;
        int h = n >> 6, dd = n & 63;
        #pragma unroll
        for (int rr = 0; rr < 4; ++rr) {
          int m = mrow0 + rr;
          int b = m >> 10, t = m & 1023;
          Cb[((size_t)((b * NH + h) * T_SEQ + t)) * HD + dd] = f2b(acc[i][j][rr] + bv);
        }
      } else {
        unsigned short* Cb = (unsigned short*)C;
        int h = n >> 6, dd = n & 63;
        int b = mrow0 >> 10, t = mrow0 & 1023;
        ushort4 pk;
        unsigned short* pp = (unsigned short*)&pk;
        #pragma unroll
        for (int rr = 0; rr < 4; ++rr)
          pp[rr] = f2b((acc[i][j][rr] + bv) * mask[mrow0 + rr]);
        *(ushort4*)&Cb[((size_t)((b * NH + h) * HD + dd)) * T_SEQ + t] = pk;
      }
    }
  }
}

// ---------------- emb: e = silu(emb) @ emb_w + emb_b ----------------
__global__ __launch_bounds__(256) void emb_gemm2(
    const float* __restrict__ emb, const float* __restrict__ emb_w,
    const float* __restrict__ emb_b, float* __restrict__ e)
{
  __shared__ float ses[B_SZ][TE_DIM];
  int n = blockIdx.x * 256 + threadIdx.x;
  for (int i = threadIdx.x; i < B_SZ * TE_DIM; i += 256) {
    int bb = i >> 11, t = i & (TE_DIM - 1);
    float v = emb[bb * TE_DIM + t];
    ses[bb][t] = v / (1.f + __expf(-v));
  }
  __syncthreads();
  float acc[B_SZ];
  #pragma unroll
  for (int bb = 0; bb < B_SZ; ++bb) acc[bb] = 0.f;
  for (int t = 0; t < TE_DIM; ++t) {
    float wv = emb_w[(size_t)t * (2 * D_MODEL) + n];
    #pragma unroll
    for (int bb = 0; bb < B_SZ; ++bb)
      acc[bb] = fmaf(ses[bb][t], wv, acc[bb]);
  }
  float bv = emb_b[n];
  #pragma unroll
  for (int bb = 0; bb < B_SZ; ++bb)
    e[bb * (2 * D_MODEL) + n] = acc[bb] + bv;
}

// ---------------- MFMA flash attention v2 ----------------
// Q,K bf16 [B,H,T,64]; Vt bf16 [B,H,64,T]; y fp32 [B,T,D]
// 4 waves/block, 32 q/wave (two 16-col frags). K/V LDS double-buffered via
// global_load_lds into pre-permuted [chunk][lane][8] layout (conflict-free).
__global__ __launch_bounds__(256, 3) void attn_mfma2(
    const unsigned short* __restrict__ Q, const unsigned short* __restrict__ K,
    const unsigned short* __restrict__ Vt, const float* __restrict__ mask,
    float* __restrict__ y)
{
  __shared__ unsigned short Kb[2][4096];   // 8 chunks * 512 shorts
  __shared__ unsigned short Vb[2][4096];
  __shared__ unsigned short Pb[4][2][16 * 72];

  int tid = threadIdx.x, w = tid >> 6, lane = tid & 63;
  int g = lane >> 4, lq = lane & 15;
  // XCD-aware remap: 8 consecutive logical blocks (one head) -> one XCD
  int bid = blockIdx.x;
  int lid = (bid & 7) * 128 + (bid >> 3);
  int qb = lid & 7, h = (lid >> 3) & 15, b = lid >> 7;
  int q0 = qb * 128 + w * 32;
  size_t hb = ((size_t)(b * NH + h)) * T_SEQ * HD;

  bf16x8 bq[2][2];
  #pragma unroll
  for (int qa = 0; qa < 2; ++qa)
    #pragma unroll
    for (int kh = 0; kh < 2; ++kh)
      bq[qa][kh] = *(const bf16x8*)(Q + hb + (size_t)(q0 + qa * 16 + lq) * HD + kh * 32 + g * 8);

  // staging source base addresses (bytes); chunk c = (pair)*2 + half
  const char* kBase = (const char*)(K + hb) + lq * 128 + g * 16;
  const char* vBase = (const char*)(Vt + hb) + lq * 2048 + g * 16;
  int c0 = 2 * w, c1 = 2 * w + 1;
  const char* kS0 = kBase + (c0 >> 1) * 2048 + (c0 & 1) * 64;
  const char* kS1 = kBase + (c1 >> 1) * 2048 + (c1 & 1) * 64;
  const char* vS0 = vBase + (c0 >> 1) * 32768 + (c0 & 1) * 64;
  const char* vS1 = vBase + (c1 >> 1) * 32768 + (c1 & 1) * 64;

  f32x4 o[4][2];
  #pragma unroll
  for (int dt = 0; dt < 4; ++dt)
    #pragma unroll
    for (int qa = 0; qa < 2; ++qa)
      o[dt][qa] = (f32x4){0.f, 0.f, 0.f, 0.f};
  float mrun[2] = {-3.0e38f, -3.0e38f}, lrun[2] = {0.f, 0.f};
  unsigned short* Pw[2] = {&Pb[w][0][0], &Pb[w][1][0]};
  const float* maskb = mask + b * T_SEQ;

  // prologue: stage tile 0
  gll16(kS0, &Kb[0][c0 * 512]);
  gll16(kS1, &Kb[0][c1 * 512]);
  gll16(vS0, &Vb[0][c0 * 512]);
  gll16(vS1, &Vb[0][c1 * 512]);
  __syncthreads();

  for (int t = 0; t < 16; ++t) {
    int cur = t & 1;
    int kv0 = t * 64;
    if (t < 15) {
      int nxt = cur ^ 1;
      size_t ko = (size_t)(kv0 + 64) * 128;
      size_t vo = (size_t)(kv0 + 64) * 2;
      gll16(kS0 + ko, &Kb[nxt][c0 * 512]);
      gll16(kS1 + ko, &Kb[nxt][c1 * 512]);
      gll16(vS0 + vo, &Vb[nxt][c0 * 512]);
      gll16(vS1 + vo, &Vb[nxt][c1 * 512]);
    }
    const unsigned short* Kc = &Kb[cur][0];
    const unsigned short* Vc = &Vb[cur][0];

    bf16x8 kf[4][2];
    #pragma unroll
    for (int kt = 0; kt < 4; ++kt)
      #pragma unroll
      for (int kh = 0; kh < 2; ++kh)
        kf[kt][kh] = *(const bf16x8*)(Kc + (kt * 2 + kh) * 512 + lane * 8);

    f32x4 st[4][2];
    #pragma unroll
    for (int kt = 0; kt < 4; ++kt)
      #pragma unroll
      for (int qa = 0; qa < 2; ++qa)
        st[kt][qa] = (f32x4){0.f, 0.f, 0.f, 0.f};

    __builtin_amdgcn_s_setprio(1);
    #pragma unroll
    for (int kt = 0; kt < 4; ++kt)
      #pragma unroll
      for (int qa = 0; qa < 2; ++qa) {
        st[kt][qa] = MFMA16(kf[kt][0], bq[qa][0], st[kt][qa]);
        st[kt][qa] = MFMA16(kf[kt][1], bq[qa][1], st[kt][qa]);
      }
    __builtin_amdgcn_s_setprio(0);

    // V frags from LDS (latency hides under softmax)
    bf16x8 vf[4][2];
    #pragma unroll
    for (int dt = 0; dt < 4; ++dt)
      #pragma unroll
      for (int kh = 0; kh < 2; ++kh)
        vf[dt][kh] = *(const bf16x8*)(Vc + (dt * 2 + kh) * 512 + lane * 8);

    // mask bias (kv-dependent only)
    #pragma unroll
    for (int kt = 0; kt < 4; ++kt) {
      float4 mk = *(const float4*)&maskb[kv0 + kt * 16 + g * 4];
      float mb[4] = {(1.f - mk.x) * -1000000.f, (1.f - mk.y) * -1000000.f,
                     (1.f - mk.z) * -1000000.f, (1.f - mk.w) * -1000000.f};
      #pragma unroll
      for (int qa = 0; qa < 2; ++qa)
        #pragma unroll
        for (int r = 0; r < 4; ++r)
          st[kt][qa][r] += mb[r];
    }

    // online softmax (per qa; column q = lq, 4 g-lanes share a q)
    float tmax[2];
    #pragma unroll
    for (int qa = 0; qa < 2; ++qa) {
      float tm = st[0][qa][0];
      #pragma unroll
      for (int kt = 0; kt < 4; ++kt)
        #pragma unroll
        for (int r = 0; r < 4; ++r)
          tm = fmaxf(tm, st[kt][qa][r]);
      tm = fmaxf(tm, __shfl_xor(tm, 16));
      tm = fmaxf(tm, __shfl_xor(tm, 32));
      tmax[qa] = tm;
    }
    bool need = (tmax[0] > mrun[0] + 8.f) || (tmax[1] > mrun[1] + 8.f);
    if (__any((int)need)) {
      #pragma unroll
      for (int qa = 0; qa < 2; ++qa) {
        float mnew = fmaxf(mrun[qa], tmax[qa]);
        float corr = __expf(mrun[qa] - mnew);
        lrun[qa] *= corr;
        #pragma unroll
        for (int dt = 0; dt < 4; ++dt) {
          o[dt][qa][0] *= corr; o[dt][qa][1] *= corr;
          o[dt][qa][2] *= corr; o[dt][qa][3] *= corr;
        }
        mrun[qa] = mnew;
      }
    }
    #pragma unroll
    for (int qa = 0; qa < 2; ++qa) {
      float psum = 0.f;
      #pragma unroll
      for (int kt = 0; kt < 4; ++kt)
        #pragma unroll
        for (int r = 0; r < 4; ++r) {
          float p = __expf(st[kt][qa][r] - mrun[qa]);
          st[kt][qa][r] = p;
          psum += p;
        }
      psum += __shfl_xor(psum, 16);
      psum += __shfl_xor(psum, 32);
      lrun[qa] += psum;
    }

    // pack P -> per-wave LDS  (P[q=lq][kv], stride 72)
    #pragma unroll
    for (int qa = 0; qa < 2; ++qa)
      #pragma unroll
      for (int kt = 0; kt < 4; ++kt) {
        ushort4 pk;
        pk.x = f2b(st[kt][qa][0]); pk.y = f2b(st[kt][qa][1]);
        pk.z = f2b(st[kt][qa][2]); pk.w = f2b(st[kt][qa][3]);
        *(ushort4*)(Pw[qa] + lq * 72 + kt * 16 + g * 4) = pk;
      }

    // PV: o[dt][qa] += V^T . P^T
    __builtin_amdgcn_s_setprio(1);
    #pragma unroll
    for (int qa = 0; qa < 2; ++qa)
      #pragma unroll
      for (int kh = 0; kh < 2; ++kh) {
        bf16x8 pa = *(const bf16x8*)(Pw[qa] + lq * 72 + kh * 32 + g * 8);
        #pragma unroll
        for (int dt = 0; dt < 4; ++dt)
          o[dt][qa] = MFMA16(vf[dt][kh], pa, o[dt][qa]);
      }
    __builtin_amdgcn_s_setprio(0);

    __syncthreads();
  }

  #pragma unroll
  for (int qa = 0; qa < 2; ++qa) {
    float inv = 1.f / lrun[qa];
    #pragma unroll
    for (int dt = 0; dt < 4; ++dt) {
      f32x4 ov;
      ov[0] = o[dt][qa][0] * inv; ov[1] = o[dt][qa][1] * inv;
      ov[2] = o[dt][qa][2] * inv; ov[3] = o[dt][qa][3] * inv;
      *(f32x4*)&y[(size_t)(b * T_SEQ + q0 + qa * 16 + lq) * D_MODEL + h * HD + dt * 16 + g * 4] = ov;
    }
  }
}

// -------- g = silu(LN(y)*(1+scale)+shift)  (bf16 out) ----------
__global__ __launch_bounds__(256) void ln2_kernel(
    const float* __restrict__ y, const float* __restrict__ w,
    const float* __restrict__ b, const float* __restrict__ e,
    unsigned short* __restrict__ gout)
{
  __shared__ float red[8];
  int row = blockIdx.x;
  int tid = threadIdx.x;
  int bb = row >> 10;
  float4 yv = *(const float4*)&y[(size_t)row * D_MODEL + tid * 4];
  float s  = yv.x + yv.y + yv.z + yv.w;
  float ss = yv.x*yv.x + yv.y*yv.y + yv.z*yv.z + yv.w*yv.w;
  #pragma unroll
  for (int off = 32; off; off >>= 1) {
    s  += __shfl_xor(s, off);
    ss += __shfl_xor(ss, off);
  }
  int wv = tid >> 6;
  if ((tid & 63) == 0) { red[wv] = s; red[4 + wv] = ss; }
  __syncthreads();
  s  = red[0] + red[1] + red[2] + red[3];
  ss = red[4] + red[5] + red[6] + red[7];
  float mean = s * (1.f / D_MODEL);
  float var  = ss * (1.f / D_MODEL) - mean * mean;
  float inv  = rsqrtf(var + 1e-5f);
  float vals[4] = {yv.x, yv.y, yv.z, yv.w};
  ushort4 o;
  unsigned short* op = (unsigned short*)&o;
  #pragma unroll
  for (int j = 0; j < 4; j++) {
    int c = tid * 4 + j;
    float val = (vals[j] - mean) * inv * w[c] + b[c];
    float sc = e[bb * (2 * D_MODEL) + c];
    float sh = e[bb * (2 * D_MODEL) + D_MODEL + c];
    val = val * (1.f + sc) + sh;
    op[j] = f2b(val / (1.f + __expf(-val)));
  }
  *(ushort4*)&gout[(size_t)row * D_MODEL + tid * 4] = o;
}

extern "C" void kernel_launch(void* const* d_in, const int* in_sizes, int n_in,
                              void* d_out, int out_size, void* d_ws, size_t ws_size,
                              hipStream_t stream) {
  const float* x      = (const float*)d_in[0];
  const float* emb    = (const float*)d_in[1];
  const float* mask   = (const float*)d_in[2];
  const float* norm_w = (const float*)d_in[3];
  const float* norm_b = (const float*)d_in[4];
  const float* q_w    = (const float*)d_in[5];
  const float* q_b    = (const float*)d_in[6];
  const float* k_w    = (const float*)d_in[7];
  const float* k_b    = (const float*)d_in[8];
  const float* v_w    = (const float*)d_in[9];
  const float* v_b    = (const float*)d_in[10];
  const float* emb_w  = (const float*)d_in[11];
  const float* emb_b  = (const float*)d_in[12];
  const float* sb_w   = (const float*)d_in[13];
  const float* sb_b   = (const float*)d_in[14];
  const float* out_w  = (const float*)d_in[15];
  const float* out_b  = (const float*)d_in[16];
  float* out = (float*)d_out;

  char* ws = (char*)d_ws;
  const size_t MB = 1u << 20;
  unsigned short* xn  = (unsigned short*)(ws);             // 16 MB bf16 [8192][1024]
  unsigned short* qb  = (unsigned short*)(ws + 16 * MB);   // 16 MB [B,H,T,64]
  unsigned short* kb  = (unsigned short*)(ws + 32 * MB);   // 16 MB [B,H,T,64]
  unsigned short* vt  = (unsigned short*)(ws + 48 * MB);   // 16 MB [B,H,64,T]
  float*          yb  = (float*)(ws + 64 * MB);            // 32 MB fp32 [B,T,D]
  unsigned short* gb  = (unsigned short*)(ws + 96 * MB);   // 16 MB bf16
  unsigned short* qwt = (unsigned short*)(ws + 112 * MB);  // 2 MB each
  unsigned short* kwt = (unsigned short*)(ws + 114 * MB);
  unsigned short* vwt = (unsigned short*)(ws + 116 * MB);
  unsigned short* owt = (unsigned short*)(ws + 118 * MB);
  float*          eb  = (float*)(ws + 120 * MB);           // 64 KB [B][2D]

  dim3 tg(32, 32);
  transpose_w<<<tg, 256, 0, stream>>>(q_w, qwt);
  transpose_w<<<tg, 256, 0, stream>>>(k_w, kwt);
  transpose_w<<<tg, 256, 0, stream>>>(v_w, vwt);
  transpose_w<<<tg, 256, 0, stream>>>(out_w, owt);

  ln_kernel<<<BT_ROWS, 256, 0, stream>>>(x, norm_w, norm_b, xn);

  dim3 gg(D_MODEL / 128, BT_ROWS / 128);
  gemm_bf16<<<gg, 256, 0, stream>>>(xn, qwt, q_b, nullptr, nullptr, qb, 1);
  gemm_bf16<<<gg, 256, 0, stream>>>(xn, kwt, k_b, nullptr, nullptr, kb, 1);
  gemm_bf16<<<gg, 256, 0, stream>>>(xn, vwt, v_b, mask, nullptr, vt, 2);

  emb_gemm2<<<(2 * D_MODEL) / 256, 256, 0, stream>>>(emb, emb_w, emb_b, eb);

  attn_mfma2<<<1024, 256, 0, stream>>>(qb, kb, vt, mask, yb);

  ln2_kernel<<<BT_ROWS, 256, 0, stream>>>(yb, sb_w, sb_b, eb, gb);

  gemm_bf16<<<gg, 256, 0, stream>>>(gb, owt, out_b, nullptr, x, out, 0);
}

// Round 4
// 253.595 us; speedup vs baseline: 15.2969x; 1.4837x over previous
//
#include <hip/hip_runtime.h>
#include <cstddef>
#include <cstdint>

#define B_SZ 8
#define T_SEQ 1024
#define D_MODEL 1024
#define NH 16
#define HD 64
#define TE_DIM 2048
#define BT_ROWS 8192

typedef short bf16x8 __attribute__((ext_vector_type(8)));
typedef float f32x4 __attribute__((ext_vector_type(4)));

#define MFMA16(a, b, c) __builtin_amdgcn_mfma_f32_16x16x32_bf16(a, b, c, 0, 0, 0)

__device__ inline unsigned short f2b(float f) {
  union { float f; unsigned u; } v; v.f = f;
  unsigned r = v.u + 0x7FFF + ((v.u >> 16) & 1);
  return (unsigned short)(r >> 16);
}

__device__ inline void gll16(const void* g, void* l) {
  __builtin_amdgcn_global_load_lds(
      (const __attribute__((address_space(1))) unsigned int*)g,
      (__attribute__((address_space(3))) unsigned int*)l, 16, 0, 0);
}

// ---------------- LayerNorm of x -> xn (bf16) ----------------
__global__ __launch_bounds__(256) void ln_kernel(
    const float* __restrict__ x, const float* __restrict__ w,
    const float* __restrict__ b, unsigned short* __restrict__ out)
{
  __shared__ float red[8];
  int row = blockIdx.x;
  int tid = threadIdx.x;
  const float* xr = x + (size_t)row * D_MODEL;
  float4 xv = *(const float4*)&xr[tid * 4];
  float s  = xv.x + xv.y + xv.z + xv.w;
  float ss = xv.x*xv.x + xv.y*xv.y + xv.z*xv.z + xv.w*xv.w;
  #pragma unroll
  for (int off = 32; off; off >>= 1) {
    s  += __shfl_xor(s, off);
    ss += __shfl_xor(ss, off);
  }
  int wv = tid >> 6;
  if ((tid & 63) == 0) { red[wv] = s; red[4 + wv] = ss; }
  __syncthreads();
  s  = red[0] + red[1] + red[2] + red[3];
  ss = red[4] + red[5] + red[6] + red[7];
  float mean = s * (1.f / D_MODEL);
  float var  = ss * (1.f / D_MODEL) - mean * mean;
  float inv  = rsqrtf(var + 1e-5f);
  float4 w4 = *(const float4*)&w[tid * 4];
  float4 b4 = *(const float4*)&b[tid * 4];
  ushort4 o;
  o.x = f2b((xv.x - mean) * inv * w4.x + b4.x);
  o.y = f2b((xv.y - mean) * inv * w4.y + b4.y);
  o.z = f2b((xv.z - mean) * inv * w4.z + b4.z);
  o.w = f2b((xv.w - mean) * inv * w4.w + b4.w);
  *(ushort4*)&out[(size_t)row * D_MODEL + tid * 4] = o;
}

// ---------------- weight transpose fp32 [K][N] -> bf16 [N][K] ----------------
__global__ __launch_bounds__(256) void transpose_w(
    const float* __restrict__ in, unsigned short* __restrict__ out)
{
  __shared__ float s[32][33];
  int tx = threadIdx.x & 31, ty = threadIdx.x >> 5;  // ty 0..7
  int r0 = blockIdx.y * 32, c0 = blockIdx.x * 32;
  #pragma unroll
  for (int rr = 0; rr < 4; ++rr)
    s[ty + rr * 8][tx] = in[(size_t)(r0 + ty + rr * 8) * D_MODEL + c0 + tx];
  __syncthreads();
  #pragma unroll
  for (int rr = 0; rr < 4; ++rr)
    out[(size_t)(c0 + ty + rr * 8) * D_MODEL + r0 + tx] = f2b(s[tx][ty + rr * 8]);
}

// ---------------- bf16 MFMA GEMM: C = A @ Bt^T + bias ----------------
// A [M][1024] bf16, Bt [N][1024] bf16 (pre-transposed weight)
// mode 0: fp32 [M][N], += resid     mode 1: bf16 [B,H,T,64]
// mode 2: bf16 [B,H,64,T], *= mask[m]
__global__ __launch_bounds__(256) void gemm_bf16(
    const unsigned short* __restrict__ A, const unsigned short* __restrict__ Bt,
    const float* __restrict__ bias, const float* __restrict__ mask,
    const float* __restrict__ resid, void* __restrict__ C, int mode)
{
  const int K = 1024;
  __shared__ unsigned short As[128 * 64];
  __shared__ unsigned short Bs[128 * 64];
  int tid = threadIdx.x;
  int lane = tid & 63, w = tid >> 6;
  int g = lane >> 4, lq = lane & 15;
  int wr = w >> 1, wc = w & 1;
  int m0 = blockIdx.y * 128, n0 = blockIdx.x * 128;
  f32x4 acc[4][4];
  #pragma unroll
  for (int i = 0; i < 4; ++i)
    #pragma unroll
    for (int j = 0; j < 4; ++j)
      acc[i][j] = (f32x4){0.f, 0.f, 0.f, 0.f};

  for (int k0 = 0; k0 < K; k0 += 64) {
    #pragma unroll
    for (int it = 0; it < 4; ++it) {
      int chunk = it * 256 + tid;
      int r = chunk >> 3, cb = chunk & 7;
      int lo = r * 128 + ((cb ^ (r & 7)) * 16);
      *(uint4*)((char*)As + lo) = *(const uint4*)(A + (size_t)(m0 + r) * K + k0 + cb * 8);
      *(uint4*)((char*)Bs + lo) = *(const uint4*)(Bt + (size_t)(n0 + r) * K + k0 + cb * 8);
    }
    __syncthreads();
    #pragma unroll
    for (int kh = 0; kh < 2; ++kh) {
      bf16x8 af[4], bfr[4];
      #pragma unroll
      for (int i = 0; i < 4; ++i) {
        int ra = wr * 64 + i * 16 + lq;
        af[i] = *(const bf16x8*)((const char*)As + ra * 128 + (((kh * 4 + g) ^ (ra & 7)) * 16));
        int rb = wc * 64 + i * 16 + lq;
        bfr[i] = *(const bf16x8*)((const char*)Bs + rb * 128 + (((kh * 4 + g) ^ (rb & 7)) * 16));
      }
      #pragma unroll
      for (int i = 0; i < 4; ++i)
        #pragma unroll
        for (int j = 0; j < 4; ++j)
          acc[i][j] = MFMA16(af[i], bfr[j], acc[i][j]);
    }
    __syncthreads();
  }

  int colbase = n0 + wc * 64;
  #pragma unroll
  for (int i = 0; i < 4; ++i) {
    int mrow0 = m0 + wr * 64 + i * 16 + g * 4;
    #pragma unroll
    for (int j = 0; j < 4; ++j) {
      int n = colbase + j * 16 + lq;
      float bv = bias[n];
      if (mode == 0) {
        float* Cf = (float*)C;
        #pragma unroll
        for (int rr = 0; rr < 4; ++rr) {
          int m = mrow0 + rr;
          Cf[(size_t)m * D_MODEL + n] = acc[i][j][rr] + bv + resid[(size_t)m * D_MODEL + n];
        }
      } else if (mode == 1) {
        unsigned short* Cb = (unsigned short*)C;
        int h = n >> 6, dd = n & 63;
        #pragma unroll
        for (int rr = 0; rr < 4; ++rr) {
          int m = mrow0 + rr;
          int b = m >> 10, t = m & 1023;
          Cb[((size_t)((b * NH + h) * T_SEQ + t)) * HD + dd] = f2b(acc[i][j][rr] + bv);
        }
      } else {
        unsigned short* Cb = (unsigned short*)C;
        int h = n >> 6, dd = n & 63;
        int b = mrow0 >> 10, t = mrow0 & 1023;
        ushort4 pk;
        unsigned short* pp = (unsigned short*)&pk;
        #pragma unroll
        for (int rr = 0; rr < 4; ++rr)
          pp[rr] = f2b((acc[i][j][rr] + bv) * mask[mrow0 + rr]);
        *(ushort4*)&Cb[((size_t)((b * NH + h) * HD + dd)) * T_SEQ + t] = pk;
      }
    }
  }
}

// ---------------- emb split-K: partial[kb][b][n] ----------------
// grid (2, 64): blockIdx.x = col-block (1024 cols), blockIdx.y = k-block (32 rows)
__global__ __launch_bounds__(256) void emb_partial(
    const float* __restrict__ emb, const float* __restrict__ emb_w,
    float* __restrict__ partial)
{
  __shared__ float ses[B_SZ][32];
  int tid = threadIdx.x;
  int t0 = blockIdx.y * 32;
  int n = blockIdx.x * 1024 + tid * 4;
  {
    int b = tid >> 5, t = tid & 31;
    float v = emb[b * TE_DIM + t0 + t];
    ses[b][t] = v / (1.f + __expf(-v));
  }
  __syncthreads();
  f32x4 acc[B_SZ];
  #pragma unroll
  for (int b = 0; b < B_SZ; ++b) acc[b] = (f32x4){0.f, 0.f, 0.f, 0.f};
  #pragma unroll 4
  for (int t = 0; t < 32; ++t) {
    f32x4 wv = *(const f32x4*)&emb_w[(size_t)(t0 + t) * (2 * D_MODEL) + n];
    #pragma unroll
    for (int b = 0; b < B_SZ; ++b) {
      float s = ses[b][t];
      acc[b][0] = fmaf(s, wv[0], acc[b][0]);
      acc[b][1] = fmaf(s, wv[1], acc[b][1]);
      acc[b][2] = fmaf(s, wv[2], acc[b][2]);
      acc[b][3] = fmaf(s, wv[3], acc[b][3]);
    }
  }
  #pragma unroll
  for (int b = 0; b < B_SZ; ++b)
    *(f32x4*)&partial[((size_t)blockIdx.y * B_SZ + b) * (2 * D_MODEL) + n] = acc[b];
}

// ---------------- emb reduce: e[b][n] = sum_kb partial + bias ----------------
__global__ __launch_bounds__(256) void emb_reduce(
    const float* __restrict__ partial, const float* __restrict__ emb_b,
    float* __restrict__ e)
{
  int idx = blockIdx.x * 256 + threadIdx.x;   // 0 .. 8*2048-1
  int b = idx >> 11, n = idx & 2047;
  float acc = emb_b[n];
  #pragma unroll 8
  for (int kb = 0; kb < 64; ++kb)
    acc += partial[((size_t)kb * B_SZ + b) * (2 * D_MODEL) + n];
  e[b * (2 * D_MODEL) + n] = acc;
}

// ---------------- MFMA flash attention v2 ----------------
// Q,K bf16 [B,H,T,64]; Vt bf16 [B,H,64,T]; y fp32 [B,T,D]
// 4 waves/block, 32 q/wave (two 16-col frags). K/V LDS double-buffered via
// global_load_lds into pre-permuted [chunk][lane][8] layout (conflict-free).
__global__ __launch_bounds__(256, 3) void attn_mfma2(
    const unsigned short* __restrict__ Q, const unsigned short* __restrict__ K,
    const unsigned short* __restrict__ Vt, const float* __restrict__ mask,
    float* __restrict__ y)
{
  __shared__ unsigned short Kb[2][4096];   // 8 chunks * 512 shorts
  __shared__ unsigned short Vb[2][4096];
  __shared__ unsigned short Pb[4][2][16 * 72];

  int tid = threadIdx.x, w = tid >> 6, lane = tid & 63;
  int g = lane >> 4, lq = lane & 15;
  // XCD-aware remap: 8 consecutive logical blocks (one head) -> one XCD
  int bid = blockIdx.x;
  int lid = (bid & 7) * 128 + (bid >> 3);
  int qb = lid & 7, h = (lid >> 3) & 15, b = lid >> 7;
  int q0 = qb * 128 + w * 32;
  size_t hb = ((size_t)(b * NH + h)) * T_SEQ * HD;

  bf16x8 bq[2][2];
  #pragma unroll
  for (int qa = 0; qa < 2; ++qa)
    #pragma unroll
    for (int kh = 0; kh < 2; ++kh)
      bq[qa][kh] = *(const bf16x8*)(Q + hb + (size_t)(q0 + qa * 16 + lq) * HD + kh * 32 + g * 8);

  // staging source base addresses (bytes); chunk c = (pair)*2 + half
  const char* kBase = (const char*)(K + hb) + lq * 128 + g * 16;
  const char* vBase = (const char*)(Vt + hb) + lq * 2048 + g * 16;
  int c0 = 2 * w, c1 = 2 * w + 1;
  const char* kS0 = kBase + (c0 >> 1) * 2048 + (c0 & 1) * 64;
  const char* kS1 = kBase + (c1 >> 1) * 2048 + (c1 & 1) * 64;
  const char* vS0 = vBase + (c0 >> 1) * 32768 + (c0 & 1) * 64;
  const char* vS1 = vBase + (c1 >> 1) * 32768 + (c1 & 1) * 64;

  f32x4 o[4][2];
  #pragma unroll
  for (int dt = 0; dt < 4; ++dt)
    #pragma unroll
    for (int qa = 0; qa < 2; ++qa)
      o[dt][qa] = (f32x4){0.f, 0.f, 0.f, 0.f};
  float mrun[2] = {-3.0e38f, -3.0e38f}, lrun[2] = {0.f, 0.f};
  unsigned short* Pw[2] = {&Pb[w][0][0], &Pb[w][1][0]};
  const float* maskb = mask + b * T_SEQ;

  // prologue: stage tile 0
  gll16(kS0, &Kb[0][c0 * 512]);
  gll16(kS1, &Kb[0][c1 * 512]);
  gll16(vS0, &Vb[0][c0 * 512]);
  gll16(vS1, &Vb[0][c1 * 512]);
  __syncthreads();

  for (int t = 0; t < 16; ++t) {
    int cur = t & 1;
    int kv0 = t * 64;
    if (t < 15) {
      int nxt = cur ^ 1;
      size_t ko = (size_t)(kv0 + 64) * 128;
      size_t vo = (size_t)(kv0 + 64) * 2;
      gll16(kS0 + ko, &Kb[nxt][c0 * 512]);
      gll16(kS1 + ko, &Kb[nxt][c1 * 512]);
      gll16(vS0 + vo, &Vb[nxt][c0 * 512]);
      gll16(vS1 + vo, &Vb[nxt][c1 * 512]);
    }
    const unsigned short* Kc = &Kb[cur][0];
    const unsigned short* Vc = &Vb[cur][0];

    bf16x8 kf[4][2];
    #pragma unroll
    for (int kt = 0; kt < 4; ++kt)
      #pragma unroll
      for (int kh = 0; kh < 2; ++kh)
        kf[kt][kh] = *(const bf16x8*)(Kc + (kt * 2 + kh) * 512 + lane * 8);

    f32x4 st[4][2];
    #pragma unroll
    for (int kt = 0; kt < 4; ++kt)
      #pragma unroll
      for (int qa = 0; qa < 2; ++qa)
        st[kt][qa] = (f32x4){0.f, 0.f, 0.f, 0.f};

    __builtin_amdgcn_s_setprio(1);
    #pragma unroll
    for (int kt = 0; kt < 4; ++kt)
      #pragma unroll
      for (int qa = 0; qa < 2; ++qa) {
        st[kt][qa] = MFMA16(kf[kt][0], bq[qa][0], st[kt][qa]);
        st[kt][qa] = MFMA16(kf[kt][1], bq[qa][1], st[kt][qa]);
      }
    __builtin_amdgcn_s_setprio(0);

    // V frags from LDS (latency hides under softmax)
    bf16x8 vf[4][2];
    #pragma unroll
    for (int dt = 0; dt < 4; ++dt)
      #pragma unroll
      for (int kh = 0; kh < 2; ++kh)
        vf[dt][kh] = *(const bf16x8*)(Vc + (dt * 2 + kh) * 512 + lane * 8);

    // mask bias (kv-dependent only)
    #pragma unroll
    for (int kt = 0; kt < 4; ++kt) {
      float4 mk = *(const float4*)&maskb[kv0 + kt * 16 + g * 4];
      float mb[4] = {(1.f - mk.x) * -1000000.f, (1.f - mk.y) * -1000000.f,
                     (1.f - mk.z) * -1000000.f, (1.f - mk.w) * -1000000.f};
      #pragma unroll
      for (int qa = 0; qa < 2; ++qa)
        #pragma unroll
        for (int r = 0; r < 4; ++r)
          st[kt][qa][r] += mb[r];
    }

    // online softmax (per qa; column q = lq, 4 g-lanes share a q)
    float tmax[2];
    #pragma unroll
    for (int qa = 0; qa < 2; ++qa) {
      float tm = st[0][qa][0];
      #pragma unroll
      for (int kt = 0; kt < 4; ++kt)
        #pragma unroll
        for (int r = 0; r < 4; ++r)
          tm = fmaxf(tm, st[kt][qa][r]);
      tm = fmaxf(tm, __shfl_xor(tm, 16));
      tm = fmaxf(tm, __shfl_xor(tm, 32));
      tmax[qa] = tm;
    }
    bool need = (tmax[0] > mrun[0] + 8.f) || (tmax[1] > mrun[1] + 8.f);
    if (__any((int)need)) {
      #pragma unroll
      for (int qa = 0; qa < 2; ++qa) {
        float mnew = fmaxf(mrun[qa], tmax[qa]);
        float corr = __expf(mrun[qa] - mnew);
        lrun[qa] *= corr;
        #pragma unroll
        for (int dt = 0; dt < 4; ++dt) {
          o[dt][qa][0] *= corr; o[dt][qa][1] *= corr;
          o[dt][qa][2] *= corr; o[dt][qa][3] *= corr;
        }
        mrun[qa] = mnew;
      }
    }
    #pragma unroll
    for (int qa = 0; qa < 2; ++qa) {
      float psum = 0.f;
      #pragma unroll
      for (int kt = 0; kt < 4; ++kt)
        #pragma unroll
        for (int r = 0; r < 4; ++r) {
          float p = __expf(st[kt][qa][r] - mrun[qa]);
          st[kt][qa][r] = p;
          psum += p;
        }
      psum += __shfl_xor(psum, 16);
      psum += __shfl_xor(psum, 32);
      lrun[qa] += psum;
    }

    // pack P -> per-wave LDS  (P[q=lq][kv], stride 72)
    #pragma unroll
    for (int qa = 0; qa < 2; ++qa)
      #pragma unroll
      for (int kt = 0; kt < 4; ++kt) {
        ushort4 pk;
        pk.x = f2b(st[kt][qa][0]); pk.y = f2b(st[kt][qa][1]);
        pk.z = f2b(st[kt][qa][2]); pk.w = f2b(st[kt][qa][3]);
        *(ushort4*)(Pw[qa] + lq * 72 + kt * 16 + g * 4) = pk;
      }

    // PV: o[dt][qa] += V^T . P^T
    __builtin_amdgcn_s_setprio(1);
    #pragma unroll
    for (int qa = 0; qa < 2; ++qa)
      #pragma unroll
      for (int kh = 0; kh < 2; ++kh) {
        bf16x8 pa = *(const bf16x8*)(Pw[qa] + lq * 72 + kh * 32 + g * 8);
        #pragma unroll
        for (int dt = 0; dt < 4; ++dt)
          o[dt][qa] = MFMA16(vf[dt][kh], pa, o[dt][qa]);
      }
    __builtin_amdgcn_s_setprio(0);

    __syncthreads();
  }

  #pragma unroll
  for (int qa = 0; qa < 2; ++qa) {
    float inv = 1.f / lrun[qa];
    #pragma unroll
    for (int dt = 0; dt < 4; ++dt) {
      f32x4 ov;
      ov[0] = o[dt][qa][0] * inv; ov[1] = o[dt][qa][1] * inv;
      ov[2] = o[dt][qa][2] * inv; ov[3] = o[dt][qa][3] * inv;
      *(f32x4*)&y[(size_t)(b * T_SEQ + q0 + qa * 16 + lq) * D_MODEL + h * HD + dt * 16 + g * 4] = ov;
    }
  }
}

// -------- g = silu(LN(y)*(1+scale)+shift)  (bf16 out) ----------
__global__ __launch_bounds__(256) void ln2_kernel(
    const float* __restrict__ y, const float* __restrict__ w,
    const float* __restrict__ b, const float* __restrict__ e,
    unsigned short* __restrict__ gout)
{
  __shared__ float red[8];
  int row = blockIdx.x;
  int tid = threadIdx.x;
  int bb = row >> 10;
  float4 yv = *(const float4*)&y[(size_t)row * D_MODEL + tid * 4];
  float s  = yv.x + yv.y + yv.z + yv.w;
  float ss = yv.x*yv.x + yv.y*yv.y + yv.z*yv.z + yv.w*yv.w;
  #pragma unroll
  for (int off = 32; off; off >>= 1) {
    s  += __shfl_xor(s, off);
    ss += __shfl_xor(ss, off);
  }
  int wv = tid >> 6;
  if ((tid & 63) == 0) { red[wv] = s; red[4 + wv] = ss; }
  __syncthreads();
  s  = red[0] + red[1] + red[2] + red[3];
  ss = red[4] + red[5] + red[6] + red[7];
  float mean = s * (1.f / D_MODEL);
  float var  = ss * (1.f / D_MODEL) - mean * mean;
  float inv  = rsqrtf(var + 1e-5f);
  float vals[4] = {yv.x, yv.y, yv.z, yv.w};
  ushort4 o;
  unsigned short* op = (unsigned short*)&o;
  #pragma unroll
  for (int j = 0; j < 4; j++) {
    int c = tid * 4 + j;
    float val = (vals[j] - mean) * inv * w[c] + b[c];
    float sc = e[bb * (2 * D_MODEL) + c];
    float sh = e[bb * (2 * D_MODEL) + D_MODEL + c];
    val = val * (1.f + sc) + sh;
    op[j] = f2b(val / (1.f + __expf(-val)));
  }
  *(ushort4*)&gout[(size_t)row * D_MODEL + tid * 4] = o;
}

extern "C" void kernel_launch(void* const* d_in, const int* in_sizes, int n_in,
                              void* d_out, int out_size, void* d_ws, size_t ws_size,
                              hipStream_t stream) {
  const float* x      = (const float*)d_in[0];
  const float* emb    = (const float*)d_in[1];
  const float* mask   = (const float*)d_in[2];
  const float* norm_w = (const float*)d_in[3];
  const float* norm_b = (const float*)d_in[4];
  const float* q_w    = (const float*)d_in[5];
  const float* q_b    = (const float*)d_in[6];
  const float* k_w    = (const float*)d_in[7];
  const float* k_b    = (const float*)d_in[8];
  const float* v_w    = (const float*)d_in[9];
  const float* v_b    = (const float*)d_in[10];
  const float* emb_w  = (const float*)d_in[11];
  const float* emb_b  = (const float*)d_in[12];
  const float* sb_w   = (const float*)d_in[13];
  const float* sb_b   = (const float*)d_in[14];
  const float* out_w  = (const float*)d_in[15];
  const float* out_b  = (const float*)d_in[16];
  float* out = (float*)d_out;

  char* ws = (char*)d_ws;
  const size_t MB = 1u << 20;
  unsigned short* xn  = (unsigned short*)(ws);             // 16 MB bf16 [8192][1024]
  unsigned short* qb  = (unsigned short*)(ws + 16 * MB);   // 16 MB [B,H,T,64]
  unsigned short* kb  = (unsigned short*)(ws + 32 * MB);   // 16 MB [B,H,T,64]
  unsigned short* vt  = (unsigned short*)(ws + 48 * MB);   // 16 MB [B,H,64,T]
  float*          yb  = (float*)(ws + 64 * MB);            // 32 MB fp32 [B,T,D]
  unsigned short* gb  = (unsigned short*)(ws + 96 * MB);   // 16 MB bf16 (ln2 out)
  float*          ep  = (float*)(ws + 96 * MB);            // 4 MB emb partials (dead before gb written)
  unsigned short* qwt = (unsigned short*)(ws + 112 * MB);  // 2 MB each
  unsigned short* kwt = (unsigned short*)(ws + 114 * MB);
  unsigned short* vwt = (unsigned short*)(ws + 116 * MB);
  unsigned short* owt = (unsigned short*)(ws + 118 * MB);
  float*          eb  = (float*)(ws + 120 * MB);           // 64 KB [B][2D]

  dim3 tg(32, 32);
  transpose_w<<<tg, 256, 0, stream>>>(q_w, qwt);
  transpose_w<<<tg, 256, 0, stream>>>(k_w, kwt);
  transpose_w<<<tg, 256, 0, stream>>>(v_w, vwt);
  transpose_w<<<tg, 256, 0, stream>>>(out_w, owt);

  ln_kernel<<<BT_ROWS, 256, 0, stream>>>(x, norm_w, norm_b, xn);

  dim3 gg(D_MODEL / 128, BT_ROWS / 128);
  gemm_bf16<<<gg, 256, 0, stream>>>(xn, qwt, q_b, nullptr, nullptr, qb, 1);
  gemm_bf16<<<gg, 256, 0, stream>>>(xn, kwt, k_b, nullptr, nullptr, kb, 1);
  gemm_bf16<<<gg, 256, 0, stream>>>(xn, vwt, v_b, mask, nullptr, vt, 2);

  emb_partial<<<dim3(2, 64), 256, 0, stream>>>(emb, emb_w, ep);
  emb_reduce<<<64, 256, 0, stream>>>(ep, emb_b, eb);

  attn_mfma2<<<1024, 256, 0, stream>>>(qb, kb, vt, mask, yb);

  ln2_kernel<<<BT_ROWS, 256, 0, stream>>>(yb, sb_w, sb_b, eb, gb);

  gemm_bf16<<<gg, 256, 0, stream>>>(gb, owt, out_b, nullptr, x, out, 0);
}